// Round 8
// baseline (1421.654 us; speedup 1.0000x reference)
//
#include <hip/hip_runtime.h>
#include <cmath>

#define HID 51
#define BATCH 256
#define BLK 768      // 12 waves
#define NR 204       // 4*HID gate rows per matrix

typedef _Float16 half2_t __attribute__((ext_vector_type(2)));

// One block per batch element (grid = 256 = #CUs). ONE barrier per tick.
// One lane = one (layer, unit, gate) row, quad-aligned: row r = 4*u + gate,
// lane gate = lane&3. Each lane computes BOTH dots for its row
//   pre = bias + Whh_l[g] . h_l(t-1) + Wih_l[g] . h_{l-1}(t)   (g = gate*51+u)
// so all 4 gate pre-acts of unit u sit in one 4-lane quad -> the cell is
// INTRA-WAVE: each lane activates its own gate (sigma, or tanh for gate 2,
// one exp+rcp), 4 mov_dpp quad-broadcasts share the activated gates, all 4
// lanes redundantly compute c (identical c_state carried per quad), gate-0
// lane writes h as fp16. No gate-partial LDS buffer, no second barrier.
// h is parity-double-buffered: ALL reads from hrow[(tau-1)&1], ALL writes
// to hrow[tau&1] (R5's verified scheme) -> race-free with one barrier.
//   waves 0-3:  L0 rows 0..203   t=tau    (26 dots; x-term via wx, no Wih)
//   waves 4-7:  L1 rows          t=tau-1  (52 dots)
//   waves 8-11: L2 rows          t=tau-2  (52 dots)
//   wave 11 lane 16: output row Wl.h2(tau-3)+bl -> obuf ring
//   wave  3 (light): 64-wide coalesced obuf flush every 64 ticks
// All h reads are wave-uniform-address b128 broadcasts (conflict-free);
// h writes are 16 consecutive b16 (2 lanes/bank = free). Layer-aligned
// waves keep every branch wave-uniform; SIMD k hosts waves {k, k+4, k+8}
// = {26,52,52}-dot load, balanced.

__device__ __forceinline__ float frcp(float v) { return __builtin_amdgcn_rcpf(v); }
__device__ __forceinline__ half2_t h2bits(int b) {
    union { int i; half2_t h; } u; u.i = b; return u.h;
}
template<int CTRL>
__device__ __forceinline__ float qbc(float v) {   // quad_perm broadcast via DPP
    int i = __builtin_bit_cast(int, v);
    i = __builtin_amdgcn_mov_dpp(i, CTRL, 0xf, 0xf, false);
    return __builtin_bit_cast(float, i);
}

__attribute__((amdgpu_waves_per_eu(3, 3)))
__global__ __launch_bounds__(BLK)
void lstm3_kernel(const float* __restrict__ x,
                  const float* __restrict__ Wih1, const float* __restrict__ Whh1,
                  const float* __restrict__ bih1, const float* __restrict__ bhh1,
                  const float* __restrict__ Wih,  const float* __restrict__ Whh,
                  const float* __restrict__ bih,  const float* __restrict__ bhh,
                  const float* __restrict__ Wl,   const float* __restrict__ bl,
                  float* __restrict__ out, int T)
{
    const int b    = blockIdx.x;
    const int tid  = threadIdx.x;
    const int wave = tid >> 6;
    const int lane = tid & 63;
    const int wl   = wave >> 2;                  // layer 0..2
    const int r    = (wave & 3) * 64 + lane;     // row within layer
    const int gate = lane & 3;
    const int u    = r >> 2;
    const bool isOut = (wave == 11) && (lane == 16);
    const bool valid = (r < NR) && !isOut;
    const int g    = gate * HID + ((u < HID) ? u : 0);

    __shared__ __align__(16) float xbuf[2048];
    __shared__ __align__(16) int   hrow[2][3][32];   // [parity][layer] fp16 pairs
    __shared__ __align__(16) float obuf[128];        // output ring (2 x 64)

    for (int i = tid; i < T; i += BLK) xbuf[i] = x[(size_t)b * T + i];
    if (tid < 192) ((int*)hrow)[tid] = 0;            // both parities, incl. pads

    // ---------------- per-lane weight rows (one-time) ----------------
    half2_t w2a[26], w2b[26];
    #pragma unroll
    for (int j = 0; j < 26; ++j) {
        w2a[j] = half2_t{(_Float16)0.f, (_Float16)0.f};
        w2b[j] = w2a[j];
    }
    const float* wA = nullptr;
    const float* wB = nullptr;
    if (valid) wA = (wl == 0) ? Whh1 + (size_t)g * HID
                              : Whh + ((size_t)(wl - 1) * NR + g) * HID;
    if (isOut) wA = Wl;
    if (valid && wl > 0) wB = Wih + ((size_t)(wl - 1) * NR + g) * HID;
    if (wA) {
        #pragma unroll
        for (int j = 0; j < 25; ++j)
            w2a[j] = half2_t{(_Float16)wA[2*j], (_Float16)wA[2*j+1]};
        w2a[25] = half2_t{(_Float16)wA[50], (_Float16)0.f};
    }
    if (wB) {
        #pragma unroll
        for (int j = 0; j < 25; ++j)
            w2b[j] = half2_t{(_Float16)wB[2*j], (_Float16)wB[2*j+1]};
        w2b[25] = half2_t{(_Float16)wB[50], (_Float16)0.f};
    }
    float bias = 0.f, wx = 0.f;
    if (valid) {
        if (wl == 0) { bias = bih1[g] + bhh1[g]; wx = Wih1[g]; }
        else         { const int q = (wl - 1) * NR + g; bias = bih[q] + bhh[q]; }
    }
    if (isOut) bias = bl[0];

    float c_state = 0.f;
    __syncthreads();

    const int TICKS = T + 4;
    for (int tau = 0; tau < TICKS; ++tau) {
        const int rp = (tau - 1) & 1;            // read parity (last tick's writes)
        const int wp = tau & 1;                  // write parity
        const int t  = tau - (isOut ? 3 : wl);   // this lane's timestep
        const bool pred = (unsigned)t < (unsigned)T;

        // ---- dots: own Whh row (+ Wih row for l>0), broadcast h reads ----
        int hwA[28];
        {
            const int4* hA = (const int4*)&hrow[rp][wl][0];      // uniform addr
            #pragma unroll
            for (int k = 0; k < 7; ++k) {
                const int4 q = hA[k];
                hwA[4*k+0] = q.x; hwA[4*k+1] = q.y; hwA[4*k+2] = q.z; hwA[4*k+3] = q.w;
            }
        }
        float a0 = bias, a1 = 0.f;
        #pragma unroll
        for (int j = 0; j < 26; ++j) {
            const half2_t hj = h2bits(hwA[j]);
            if (j & 1) a1 = __builtin_amdgcn_fdot2(w2a[j], hj, a1, false);
            else       a0 = __builtin_amdgcn_fdot2(w2a[j], hj, a0, false);
        }
        if (wl > 0) {                            // wave-uniform branch
            int hwB[28];
            const int4* hB = (const int4*)&hrow[rp][wl - 1][0];  // uniform addr
            #pragma unroll
            for (int k = 0; k < 7; ++k) {
                const int4 q = hB[k];
                hwB[4*k+0] = q.x; hwB[4*k+1] = q.y; hwB[4*k+2] = q.z; hwB[4*k+3] = q.w;
            }
            #pragma unroll
            for (int j = 0; j < 26; ++j) {
                const half2_t hj = h2bits(hwB[j]);
                if (j & 1) a1 = __builtin_amdgcn_fdot2(w2b[j], hj, a1, false);
                else       a0 = __builtin_amdgcn_fdot2(w2b[j], hj, a0, false);
            }
        }
        float v = a0 + a1;
        if (wl == 0) v = fmaf(wx, xbuf[pred ? t : 0], v);   // uniform x broadcast

        // ---- activation of OWN gate: sigma, or tanh for gate 2 ----
        const bool isg = (gate == 2);
        const float arg = isg ? (v + v) : (-v);
        const float e   = __expf(arg);           // inf-safe both directions
        const float rr  = frcp(1.f + e);
        const float act = isg ? fmaf(-2.f, rr, 1.f) : rr;   // tanh(v) : sigmoid(v)

        // ---- quad-share activated gates (DPP broadcasts), cell update ----
        const float si = qbc<0x00>(act);         // sigma(i)  from quad lane 0
        const float sf = qbc<0x55>(act);         // sigma(f)
        const float tg = qbc<0xAA>(act);         // tanh(g)
        const float so = qbc<0xFF>(act);         // sigma(o)
        const float c  = fmaf(sf, c_state, si * tg);
        c_state = pred ? c : c_state;
        const float e2 = __expf(c + c);
        const float th = fmaf(-2.f, frcp(e2 + 1.f), 1.f);   // tanh(c)
        const float h  = so * th;

        if (pred && valid && gate == 0)
            ((_Float16*)&hrow[wp][wl][0])[u] = (_Float16)h;
        if (isOut && pred)
            obuf[t & 127] = v;                   // v = Wl.h2 + bl (bias folded)
        if (wave == 3 && (tau & 63) == 3 && tau >= 67) {
            const int t0 = tau - 67;             // multiple of 64; all slots
            out[(size_t)b * T + t0 + lane] = obuf[(t0 & 64) + lane];   // complete
        }
        __syncthreads();                         // the ONLY barrier per tick
    }
}

extern "C" void kernel_launch(void* const* d_in, const int* in_sizes, int n_in,
                              void* d_out, int out_size, void* d_ws, size_t ws_size,
                              hipStream_t stream) {
    const float* x    = (const float*)d_in[0];
    const float* Wih1 = (const float*)d_in[1];
    const float* Whh1 = (const float*)d_in[2];
    const float* bih1 = (const float*)d_in[3];
    const float* bhh1 = (const float*)d_in[4];
    const float* Wih  = (const float*)d_in[5];
    const float* Whh  = (const float*)d_in[6];
    const float* bih  = (const float*)d_in[7];
    const float* bhh  = (const float*)d_in[8];
    const float* Wl   = (const float*)d_in[9];
    const float* bl   = (const float*)d_in[10];
    float* out = (float*)d_out;

    const int T = in_sizes[0] / BATCH;   // 2048 (flush assumes T % 64 == 0)
    lstm3_kernel<<<BATCH, BLK, 0, stream>>>(x, Wih1, Whh1, bih1, bhh1,
                                            Wih, Whh, bih, bhh, Wl, bl, out, T);
}